// Round 6
// baseline (603.623 us; speedup 1.0000x reference)
//
#include <hip/hip_runtime.h>

#define DIM 128
#define NCB 8
#define KSZ 2048
#define BATCH 16
#define TOK 2048
#define NTOK (BATCH * TOK)            // 32768
#define NELEM (BATCH * DIM * TOK)     // 4194304
#define T_TILE 128                    // tokens per block
#define NTHR 512                      // 8 waves
#define CHUNK 32                      // codes per chunk per group
#define NCHUNK 16                     // chunks per group per stage
#define GCODES 512                    // codes per group (4 groups)

typedef float f32x4 __attribute__((ext_vector_type(4)));
typedef _Float16 f16x8 __attribute__((ext_vector_type(8)));

// ---------------------------------------------------------------------------
// prep: codebooks -> fp16 plane (RNE cast)
// ---------------------------------------------------------------------------
__global__ void rvq_prep_f16(const float* __restrict__ cbs,
                             _Float16* __restrict__ chf) {
    int i = blockIdx.x * 256 + threadIdx.x;
    chf[i] = (_Float16)cbs[i];
}

// ---------------------------------------------------------------------------
// exact fp32 cnorm (round-1 formula) + zero loss accumulator
// ---------------------------------------------------------------------------
__global__ void rvq_cnorm(const float* __restrict__ cbs,
                          float* __restrict__ cnorm,
                          float* __restrict__ loss_acc) {
    if (blockIdx.x == 0 && threadIdx.x == 0) *loss_acc = 0.0f;
    int k = blockIdx.x * 256 + threadIdx.x;
    const float4* row = (const float4*)(cbs + (size_t)k * DIM);
    float s = 0.0f;
#pragma unroll
    for (int i = 0; i < DIM / 4; ++i) {
        float4 v = row[i];
        s += v.x * v.x + v.y * v.y + v.z * v.z + v.w * v.w;
    }
    cnorm[k] = s;
}

// ---------------------------------------------------------------------------
// fused RVQ. 8 waves = 4 groups x 2 waves. Group g scans codes [g*512,+512)
// in 16 chunks of 32. Each wave: mt=4 (64 tokens) x nt=2 x dc=4 = 32 MFMA
// per chunk fed by 8 ds_read_b128. Per-lane top-2 keys per (row, col16)
// class (32 codes) with (chunk,nt) in 5 low mantissa bits; per-group TOP-4
// merge -> 16 candidates/token rescored with the exact round-1 fp32 formula.
// grid 256 blocks (1/CU), 512 threads (2 waves/SIMD).
// ---------------------------------------------------------------------------
__global__ __launch_bounds__(NTHR, 2) void rvq_fused(
        const float* __restrict__ x,           // (B, D, T)
        const float* __restrict__ cbs,         // (NCB, KSZ, DIM) fp32
        const _Float16* __restrict__ chf,      // fp16 codebooks
        const float* __restrict__ cng,         // (NCB*KSZ) exact cnorm
        float* __restrict__ out,               // (B, D, T)
        float* __restrict__ codes,             // (B, NCB, T) as float
        float* __restrict__ loss_acc) {
    __shared__ float res_lds[T_TILE][DIM + 4];          // 67584 B
    // shbuf: chunk staging (4 groups x 2 bufs x 8KB = 64KB) OVERLAID with
    // candidate publish area cand[t*144 + g*36 + col*2 + s] (73728 B).
    // Safe: staging dead after last chunk barrier; cand dead before next
    // stage's first staging write (update-section barrier separates them).
    __shared__ __align__(16) char shbuf[T_TILE * 144 * 4];  // 73728 B
    __shared__ float cn_lds[KSZ];                        // 8192 B => ~146 KB

    _Float16* Ball = (_Float16*)shbuf;
    float*    cand = (float*)shbuf;

    const int tid   = threadIdx.x;
    const int lane  = tid & 63;
    const int wv    = __builtin_amdgcn_readfirstlane(tid >> 6);  // 0..7
    const int col16 = lane & 15;
    const int quad  = lane >> 4;
    const int g     = wv >> 1;        // group 0..3
    const int sub   = wv & 1;         // wave within group

    const int token0 = blockIdx.x * T_TILE;
    const int b      = token0 >> 11;
    const int t_in_b = token0 & (TOK - 1);

    // ---- init: x[b][d][t0..] -> res_lds[t][d] ----
    {
        const float* xb = x + (size_t)b * DIM * TOK + t_in_b;
#pragma unroll
        for (int it = 0; it < 8; ++it) {
            int idx = it * NTHR + tid;           // 0..4095
            int d  = idx >> 5;
            int t4 = (idx & 31) * 4;
            float4 v = *(const float4*)(xb + (size_t)d * TOK + t4);
            res_lds[t4 + 0][d] = v.x;
            res_lds[t4 + 1][d] = v.y;
            res_lds[t4 + 2][d] = v.z;
            res_lds[t4 + 3][d] = v.w;
        }
    }
    __syncthreads();

    float my_loss = 0.0f;
    const float INFV = __builtin_inff();

#pragma unroll 1
    for (int s = 0; s < NCB; ++s) {
        const _Float16* __restrict__ ch_s = chf + (size_t)s * KSZ * DIM;
        const float* __restrict__ cb_s = cbs + (size_t)s * KSZ * DIM;
        const float* __restrict__ cn_s = cng + (size_t)s * KSZ;

        // ---- stage this stage's cnorm into LDS ----
        {
            float4 v = *(const float4*)(cn_s + tid * 4);
            *(float4*)&cn_lds[tid * 4] = v;
        }

        // ---- A fragments (fp16) from LDS residual; wave owns 64 tokens ----
        // A[m=lane&15][k=quad*8+j], token = sub*64 + mt*16 + col16
        f16x8 ah[4][4];
#pragma unroll
        for (int mt = 0; mt < 4; ++mt) {
#pragma unroll
            for (int dc = 0; dc < 4; ++dc) {
                int t  = sub * 64 + mt * 16 + col16;
                int d0 = dc * 32 + quad * 8;
                float4 u = *(const float4*)&res_lds[t][d0];
                float4 w = *(const float4*)&res_lds[t][d0 + 4];
                f16x8 hv;
                hv[0] = (_Float16)u.x; hv[1] = (_Float16)u.y;
                hv[2] = (_Float16)u.z; hv[3] = (_Float16)u.w;
                hv[4] = (_Float16)w.x; hv[5] = (_Float16)w.y;
                hv[6] = (_Float16)w.z; hv[7] = (_Float16)w.w;
                ah[mt][dc] = hv;
            }
        }

        // top-2 keys per slot (mt*4+r); key low5 = (chunk<<1)|nt
        float k1[16], k2[16];
#pragma unroll
        for (int sl = 0; sl < 16; ++sl) { k1[sl] = INFV; k2[sl] = INFV; }

        f16x8 stg[4];
        _Float16* Bg = Ball + g * 2 * 4096;   // this group's two 8KB buffers

        // ---- prologue: stage chunk 0 into buf 0 ----
#pragma unroll
        for (int j = 0; j < 4; ++j) {
            int f = sub * 4 + j;
            int nt = f >> 2, dc = f & 3;
            stg[j] = *(const f16x8*)(ch_s +
                (size_t)(g * GCODES + nt * 16 + col16) * DIM + dc * 32 + quad * 8);
        }
#pragma unroll
        for (int j = 0; j < 4; ++j) {
            int f = sub * 4 + j;
            *(f16x8*)(Bg + f * 512 + lane * 8) = stg[j];
        }
        __syncthreads();

        // ---- chunk loop (dbuf, 1 barrier/chunk) ----
        f32x4 acc[4][2];
#pragma unroll 1
        for (int c = 0; c < NCHUNK; ++c) {
            const int cur = c & 1;
            if (c < NCHUNK - 1) {
#pragma unroll
                for (int j = 0; j < 4; ++j) {
                    int f = sub * 4 + j;
                    int nt = f >> 2, dc = f & 3;
                    stg[j] = *(const f16x8*)(ch_s +
                        (size_t)(g * GCODES + (c + 1) * CHUNK + nt * 16 + col16) * DIM
                        + dc * 32 + quad * 8);
                }
            }
#pragma unroll
            for (int mt = 0; mt < 4; ++mt) {
                acc[mt][0] = (f32x4){0.f, 0.f, 0.f, 0.f};
                acc[mt][1] = (f32x4){0.f, 0.f, 0.f, 0.f};
            }
#pragma unroll
            for (int dc = 0; dc < 4; ++dc) {
                f16x8 b0 = *(const f16x8*)(Bg + cur * 4096 + dc * 512 + lane * 8);
                f16x8 b1 = *(const f16x8*)(Bg + cur * 4096 + (4 + dc) * 512 + lane * 8);
#pragma unroll
                for (int mt = 0; mt < 4; ++mt) {
                    acc[mt][0] = __builtin_amdgcn_mfma_f32_16x16x32_f16(
                        ah[mt][dc], b0, acc[mt][0], 0, 0, 0);
                    acc[mt][1] = __builtin_amdgcn_mfma_f32_16x16x32_f16(
                        ah[mt][dc], b1, acc[mt][1], 0, 0, 0);
                }
            }
            // fold: approx score = cnorm - 2*dot (rn constant per token)
            {
                float cn0 = cn_lds[g * GCODES + c * CHUNK + col16];
                float cn1 = cn_lds[g * GCODES + c * CHUNK + 16 + col16];
                unsigned em = (unsigned)(c << 1);
#pragma unroll
                for (int mt = 0; mt < 4; ++mt) {
#pragma unroll
                    for (int r = 0; r < 4; ++r) {
                        float p0 = fmaf(-2.0f, acc[mt][0][r], cn0);
                        float p1 = fmaf(-2.0f, acc[mt][1][r], cn1);
                        float q0 = __uint_as_float(
                            (__float_as_uint(p0) & 0xFFFFFFE0u) | em);
                        float q1 = __uint_as_float(
                            (__float_as_uint(p1) & 0xFFFFFFE0u) | em | 1u);
                        float m = fminf(q0, q1);
                        int sl = mt * 4 + r;
                        k2[sl] = fminf(k2[sl], fmaxf(k1[sl], m));
                        k1[sl] = fminf(k1[sl], m);
                    }
                }
            }
            if (c < NCHUNK - 1) {
#pragma unroll
                for (int j = 0; j < 4; ++j) {
                    int f = sub * 4 + j;
                    *(f16x8*)(Bg + (cur ^ 1) * 4096 + f * 512 + lane * 8) = stg[j];
                }
            }
            __syncthreads();
        }

        // ---- publish per-lane top-2 keys (overlay on staging area) ----
#pragma unroll
        for (int mt = 0; mt < 4; ++mt) {
#pragma unroll
            for (int r = 0; r < 4; ++r) {
                int t = sub * 64 + mt * 16 + quad * 4 + r;
                int sl = mt * 4 + r;
                float2 pr; pr.x = k1[sl]; pr.y = k2[sl];
                *(float2*)&cand[t * 144 + g * 36 + col16 * 2] = pr;
            }
        }
        __syncthreads();

        // ---- merge: per-group TOP-4 of 32 keys; exact rescore of 16 ----
        {
            const int t  = tid >> 2;
            const int gg = tid & 3;
            float bk[4];
            int   bcol[4];
#pragma unroll
            for (int jj = 0; jj < 4; ++jj) { bk[jj] = INFV; bcol[jj] = 0; }
            const float* base = &cand[t * 144 + gg * 36];
#pragma unroll
            for (int j = 0; j < 8; ++j) {
                float4 v4 = *(const float4*)(base + j * 4);
                float vv[4] = {v4.x, v4.y, v4.z, v4.w};
#pragma unroll
                for (int e = 0; e < 4; ++e) {
                    float v = vv[e];
                    int col = (j * 4 + e) >> 1;
#pragma unroll
                    for (int jj = 0; jj < 4; ++jj) {
                        bool lt = v < bk[jj];
                        float tv = bk[jj]; int tc = bcol[jj];
                        bk[jj] = lt ? v : bk[jj];
                        bcol[jj] = lt ? col : bcol[jj];
                        v = lt ? tv : v;
                        col = lt ? tc : col;
                    }
                }
            }
            int cds[4];
#pragma unroll
            for (int jj = 0; jj < 4; ++jj) {
                unsigned e = __float_as_uint(bk[jj]) & 0x1Fu;
                cds[jj] = gg * GCODES + (int)((e >> 1) << 5) +
                          (int)((e & 1) << 4) + bcol[jj];
            }
            // exact fp32 rescore of 4 candidates (round-1 association)
            const float* p0 = cb_s + (size_t)cds[0] * DIM;
            const float* p1 = cb_s + (size_t)cds[1] * DIM;
            const float* p2 = cb_s + (size_t)cds[2] * DIM;
            const float* p3 = cb_s + (size_t)cds[3] * DIM;
            float n0 = 0, n1 = 0, n2 = 0, n3 = 0;
            float a[4][4];
#pragma unroll
            for (int jj = 0; jj < 4; ++jj)
#pragma unroll
                for (int e = 0; e < 4; ++e) a[jj][e] = 0.0f;
#pragma unroll 8
            for (int d4 = 0; d4 < DIM / 4; ++d4) {
                float4 r4 = *(const float4*)&res_lds[t][d4 * 4];
                n0 = fmaf(r4.x, r4.x, n0); n1 = fmaf(r4.y, r4.y, n1);
                n2 = fmaf(r4.z, r4.z, n2); n3 = fmaf(r4.w, r4.w, n3);
                float4 q0 = *(const float4*)(p0 + d4 * 4);
                a[0][0] = fmaf(r4.x, q0.x, a[0][0]);
                a[0][1] = fmaf(r4.y, q0.y, a[0][1]);
                a[0][2] = fmaf(r4.z, q0.z, a[0][2]);
                a[0][3] = fmaf(r4.w, q0.w, a[0][3]);
                float4 q1 = *(const float4*)(p1 + d4 * 4);
                a[1][0] = fmaf(r4.x, q1.x, a[1][0]);
                a[1][1] = fmaf(r4.y, q1.y, a[1][1]);
                a[1][2] = fmaf(r4.z, q1.z, a[1][2]);
                a[1][3] = fmaf(r4.w, q1.w, a[1][3]);
                float4 q2 = *(const float4*)(p2 + d4 * 4);
                a[2][0] = fmaf(r4.x, q2.x, a[2][0]);
                a[2][1] = fmaf(r4.y, q2.y, a[2][1]);
                a[2][2] = fmaf(r4.z, q2.z, a[2][2]);
                a[2][3] = fmaf(r4.w, q2.w, a[2][3]);
                float4 q3 = *(const float4*)(p3 + d4 * 4);
                a[3][0] = fmaf(r4.x, q3.x, a[3][0]);
                a[3][1] = fmaf(r4.y, q3.y, a[3][1]);
                a[3][2] = fmaf(r4.z, q3.z, a[3][2]);
                a[3][3] = fmaf(r4.w, q3.w, a[3][3]);
            }
            float rn = (n0 + n1) + (n2 + n3);
            float bd = INFV; int bc = 0x7FFFFFFF;
#pragma unroll
            for (int jj = 0; jj < 4; ++jj) {
                float dot = (a[jj][0] + a[jj][1]) + (a[jj][2] + a[jj][3]);
                float dist = fmaf(-2.0f, dot, rn) + cn_s[cds[jj]];
                if (dist < bd || (dist == bd && cds[jj] < bc)) {
                    bd = dist; bc = cds[jj];
                }
            }
#pragma unroll
            for (int mk = 1; mk <= 2; mk <<= 1) {
                float od = __shfl_xor(bd, mk, 64);
                int   oc = __shfl_xor(bc, mk, 64);
                if (od < bd || (od == bd && oc < bc)) { bd = od; bc = oc; }
            }
            if (gg == 0)
                codes[(size_t)b * (NCB * TOK) + (size_t)s * TOK + t_in_b + t] =
                    (float)bc;
            // update my 32-dim slice of the token's residual + loss partial
            const float* qrow = cb_s + (size_t)bc * DIM;
            float lp = 0.0f;
#pragma unroll
            for (int d4 = 0; d4 < 8; ++d4) {
                int d = gg * 32 + d4 * 4;
                float4 r4 = *(const float4*)&res_lds[t][d];
                float4 q4 = *(const float4*)(qrow + d);
                float4 nr;
                nr.x = r4.x - q4.x; nr.y = r4.y - q4.y;
                nr.z = r4.z - q4.z; nr.w = r4.w - q4.w;
                *(float4*)&res_lds[t][d] = nr;
                lp += nr.x * nr.x + nr.y * nr.y + nr.z * nr.z + nr.w * nr.w;
            }
            my_loss += lp;
        }
        __syncthreads();
    }

    // ---- epilogue: out[b][d][t] = x - residual ----
    {
        const float* xb = x + (size_t)b * DIM * TOK + t_in_b;
        float* ob = out + (size_t)b * DIM * TOK + t_in_b;
#pragma unroll
        for (int it = 0; it < 8; ++it) {
            int idx = it * NTHR + tid;
            int d  = idx >> 5;
            int t4 = (idx & 31) * 4;
            float4 v = *(const float4*)(xb + (size_t)d * TOK + t4);
            float4 o;
            o.x = v.x - res_lds[t4 + 0][d];
            o.y = v.y - res_lds[t4 + 1][d];
            o.z = v.z - res_lds[t4 + 2][d];
            o.w = v.w - res_lds[t4 + 3][d];
            *(float4*)(ob + (size_t)d * TOK + t4) = o;
        }
    }

    // ---- loss reduction ----
#pragma unroll
    for (int off = 32; off > 0; off >>= 1)
        my_loss += __shfl_down(my_loss, off, 64);
    if (lane == 0) atomicAdd(loss_acc, my_loss);
}

// ---------------------------------------------------------------------------
__global__ void rvq_loss_fin(const float* __restrict__ loss_acc,
                             float* __restrict__ loss_out) {
    *loss_out = *loss_acc * (1.0f / (float)NELEM);
}

// ---------------------------------------------------------------------------
extern "C" void kernel_launch(void* const* d_in, const int* in_sizes, int n_in,
                              void* d_out, int out_size, void* d_ws, size_t ws_size,
                              hipStream_t stream) {
    const float* x   = (const float*)d_in[0];   // (B, D, T)
    const float* cbs = (const float*)d_in[1];   // (NCB, KSZ, DIM)

    float* out      = (float*)d_out;
    float* codes    = out + NELEM;
    float* loss_out = out + NELEM + (size_t)BATCH * NCB * TOK;

    float* wsf      = (float*)d_ws;
    float* loss_acc = wsf;
    _Float16* chf   = (_Float16*)(wsf + 256);
    float* cng      = (float*)(chf + (size_t)NCB * KSZ * DIM);

    hipLaunchKernelGGL(rvq_prep_f16, dim3((NCB * KSZ * DIM) / 256), dim3(256),
                       0, stream, cbs, chf);
    hipLaunchKernelGGL(rvq_cnorm, dim3((NCB * KSZ) / 256), dim3(256), 0, stream,
                       cbs, cng, loss_acc);
    hipLaunchKernelGGL(rvq_fused, dim3(NTOK / T_TILE), dim3(NTHR), 0, stream,
                       x, cbs, chf, cng, out, codes, loss_acc);
    hipLaunchKernelGGL(rvq_loss_fin, dim3(1), dim3(1), 0, stream,
                       loss_acc, loss_out);
}